// Round 1
// baseline (1942.579 us; speedup 1.0000x reference)
//
#include <hip/hip_runtime.h>
#include <cstdint>

#define NROW 66560   // 2*NX + J rows through both MLPs
#define NXP  32768   // nx
#define NV   1024    // J
#define FD   100     // dn output dim
#define GD   28      // input / an output dim
#define HD   300     // hidden dim

// ---------------------------------------------------------------------------
// Tiled fp32 GEMM: C[N,M] = act(A[N,K] @ W[K,M] + bias (+ resid))
// BM=128, BN=64, BK=16, 256 threads, 8x4 microtile.
// ---------------------------------------------------------------------------
template<bool RELU, bool RESID>
__global__ __launch_bounds__(256) void gemm_k(
    const float* __restrict__ A, const float* __restrict__ W,
    const float* __restrict__ bias, const float* __restrict__ resid,
    float* __restrict__ C, int N, int K, int M)
{
  constexpr int BM = 128, BN = 64, BK = 16;
  __shared__ float As[BK][BM + 4];
  __shared__ float Ws[BK][BN + 4];
  const int tid = threadIdx.x;
  const int tx = tid & 15;   // col group (4 cols)
  const int ty = tid >> 4;   // row group (8 rows)
  const int row0 = blockIdx.x * BM;
  const int col0 = blockIdx.y * BN;

  float acc[8][4];
#pragma unroll
  for (int i = 0; i < 8; ++i)
#pragma unroll
    for (int j = 0; j < 4; ++j) acc[i][j] = 0.f;

  for (int k0 = 0; k0 < K; k0 += BK) {
    __syncthreads();
    // A tile 128x16 = 512 float4 (transpose into LDS). K is a multiple of 4.
#pragma unroll
    for (int l = 0; l < 2; ++l) {
      int idx = tid + l * 256;
      int r = idx >> 2, kc = idx & 3;
      float4 a = make_float4(0.f, 0.f, 0.f, 0.f);
      if (k0 + kc * 4 < K)
        a = *reinterpret_cast<const float4*>(&A[(size_t)(row0 + r) * K + k0 + kc * 4]);
      As[kc * 4 + 0][r] = a.x; As[kc * 4 + 1][r] = a.y;
      As[kc * 4 + 2][r] = a.z; As[kc * 4 + 3][r] = a.w;
    }
    // W tile 16x64 = 256 float4 (direct). M is a multiple of 4.
    {
      int kr = tid >> 4, c = tid & 15;
      float4 w = make_float4(0.f, 0.f, 0.f, 0.f);
      if ((k0 + kr < K) && (col0 + c * 4 < M))
        w = *reinterpret_cast<const float4*>(&W[(size_t)(k0 + kr) * M + col0 + c * 4]);
      *reinterpret_cast<float4*>(&Ws[kr][c * 4]) = w;
    }
    __syncthreads();
#pragma unroll
    for (int kk = 0; kk < BK; ++kk) {
      float4 a0 = *reinterpret_cast<const float4*>(&As[kk][ty * 8]);
      float4 a1 = *reinterpret_cast<const float4*>(&As[kk][ty * 8 + 4]);
      float4 w  = *reinterpret_cast<const float4*>(&Ws[kk][tx * 4]);
      float av[8] = {a0.x, a0.y, a0.z, a0.w, a1.x, a1.y, a1.z, a1.w};
      float wv[4] = {w.x, w.y, w.z, w.w};
#pragma unroll
      for (int i = 0; i < 8; ++i)
#pragma unroll
        for (int j = 0; j < 4; ++j)
          acc[i][j] = fmaf(av[i], wv[j], acc[i][j]);
    }
  }

  if (col0 + tx * 4 >= M) return;
  float4 b = *reinterpret_cast<const float4*>(&bias[col0 + tx * 4]);
  float bv[4] = {b.x, b.y, b.z, b.w};
#pragma unroll
  for (int i = 0; i < 8; ++i) {
    int row = row0 + ty * 8 + i;
    float v[4];
#pragma unroll
    for (int j = 0; j < 4; ++j) {
      float x = acc[i][j] + bv[j];
      if (RELU) x = fmaxf(x, 0.f);
      v[j] = x;
    }
    if (RESID) {
      float4 rr = *reinterpret_cast<const float4*>(&resid[(size_t)row * M + col0 + tx * 4]);
      v[0] += rr.x; v[1] += rr.y; v[2] += rr.z; v[3] += rr.w;
    }
    *reinterpret_cast<float4*>(&C[(size_t)row * M + col0 + tx * 4]) =
        make_float4(v[0], v[1], v[2], v[3]);
  }
}

// ---------------------------------------------------------------------------
// Row squared-norms of f_all (100 dims) and g_all (28 dims). One wave per row.
// ---------------------------------------------------------------------------
__global__ __launch_bounds__(256) void norms_k(
    const float* __restrict__ f_all, const float* __restrict__ g_all,
    float* __restrict__ fn, float* __restrict__ gn)
{
  int wave = threadIdx.x >> 6, lane = threadIdx.x & 63;
  int row = blockIdx.x * 4 + wave;
  const float* f = f_all + (size_t)row * FD;
  const float* g = g_all + (size_t)row * GD;
  float s = f[lane] * f[lane];
  if (lane < FD - 64) { float t = f[lane + 64]; s += t * t; }
  float sg = 0.f;
  if (lane < GD) { float t = g[lane]; sg = t * t; }
#pragma unroll
  for (int m = 32; m >= 1; m >>= 1) { s += __shfl_xor(s, m); sg += __shfl_xor(sg, m); }
  if (lane == 0) { fn[row] = s; gn[row] = sg; }
}

// ---------------------------------------------------------------------------
// Pass 1: per (i,j) tile compute Kxv,Kyv -> fm; write fm; accumulate
// colsum[j] (double atomics) and total sum(fm^2) (double atomics, 64 slots).
// 64x64 tile, 256 threads, 4x4 microtile; 4 accumulator sets (Xf,Yf,Xg,Yg).
// ---------------------------------------------------------------------------
__global__ __launch_bounds__(256) void dist1_k(
    const float* __restrict__ f_all, const float* __restrict__ g_all,
    const float* __restrict__ fn, const float* __restrict__ gn,
    const float* __restrict__ p_eps, const float* __restrict__ p_sig,
    const float* __restrict__ p_sig0, const float* __restrict__ p_cst,
    float* __restrict__ fm, double* __restrict__ colsum,
    double* __restrict__ ss_parts)
{
  __shared__ float Xs[GD][68], Ys[GD][68], Vs[GD][68];  // f-phase uses rows 0..19
  __shared__ float fnX[64], fnY[64], fnV[64], gnX[64], gnY[64], gnV[64];
  __shared__ float red[16][68];
  __shared__ float ssred[4];
  const int tid = threadIdx.x;
  const int tx = tid & 15, ty = tid >> 4;
  const int i0 = blockIdx.x * 64, j0 = blockIdx.y * 64;

  if (tid < 64) {
    fnX[tid] = fn[i0 + tid]; fnY[tid] = fn[NXP + i0 + tid]; fnV[tid] = fn[2 * NXP + j0 + tid];
    gnX[tid] = gn[i0 + tid]; gnY[tid] = gn[NXP + i0 + tid]; gnV[tid] = gn[2 * NXP + j0 + tid];
  }

  float Sxf[4][4] = {}, Syf[4][4] = {}, Sxg[4][4] = {}, Syg[4][4] = {};
  const float* fX = f_all;
  const float* fY = f_all + (size_t)NXP * FD;
  const float* fV = f_all + (size_t)2 * NXP * FD;
  const float* gX = g_all;
  const float* gY = g_all + (size_t)NXP * GD;
  const float* gV = g_all + (size_t)2 * NXP * GD;

  // f phase: K=100 in 5 chunks of 20
  for (int k0 = 0; k0 < FD; k0 += 20) {
    __syncthreads();
    for (int l = tid; l < 320; l += 256) {
      int r = l / 5, kc = l % 5;
      float4 a = *reinterpret_cast<const float4*>(&fX[(size_t)(i0 + r) * FD + k0 + kc * 4]);
      float4 b = *reinterpret_cast<const float4*>(&fY[(size_t)(i0 + r) * FD + k0 + kc * 4]);
      float4 c = *reinterpret_cast<const float4*>(&fV[(size_t)(j0 + r) * FD + k0 + kc * 4]);
      Xs[kc*4+0][r]=a.x; Xs[kc*4+1][r]=a.y; Xs[kc*4+2][r]=a.z; Xs[kc*4+3][r]=a.w;
      Ys[kc*4+0][r]=b.x; Ys[kc*4+1][r]=b.y; Ys[kc*4+2][r]=b.z; Ys[kc*4+3][r]=b.w;
      Vs[kc*4+0][r]=c.x; Vs[kc*4+1][r]=c.y; Vs[kc*4+2][r]=c.z; Vs[kc*4+3][r]=c.w;
    }
    __syncthreads();
#pragma unroll
    for (int kk = 0; kk < 20; ++kk) {
      float4 ax = *reinterpret_cast<const float4*>(&Xs[kk][ty * 4]);
      float4 ay = *reinterpret_cast<const float4*>(&Ys[kk][ty * 4]);
      float4 bv = *reinterpret_cast<const float4*>(&Vs[kk][tx * 4]);
      float axv[4] = {ax.x, ax.y, ax.z, ax.w};
      float ayv[4] = {ay.x, ay.y, ay.z, ay.w};
      float bvv[4] = {bv.x, bv.y, bv.z, bv.w};
#pragma unroll
      for (int i = 0; i < 4; ++i)
#pragma unroll
        for (int j = 0; j < 4; ++j) {
          Sxf[i][j] = fmaf(axv[i], bvv[j], Sxf[i][j]);
          Syf[i][j] = fmaf(ayv[i], bvv[j], Syf[i][j]);
        }
    }
  }

  // g phase: K=28, single chunk
  __syncthreads();
  for (int l = tid; l < 448; l += 256) {
    int r = l / 7, kc = l % 7;
    float4 a = *reinterpret_cast<const float4*>(&gX[(size_t)(i0 + r) * GD + kc * 4]);
    float4 b = *reinterpret_cast<const float4*>(&gY[(size_t)(i0 + r) * GD + kc * 4]);
    float4 c = *reinterpret_cast<const float4*>(&gV[(size_t)(j0 + r) * GD + kc * 4]);
    Xs[kc*4+0][r]=a.x; Xs[kc*4+1][r]=a.y; Xs[kc*4+2][r]=a.z; Xs[kc*4+3][r]=a.w;
    Ys[kc*4+0][r]=b.x; Ys[kc*4+1][r]=b.y; Ys[kc*4+2][r]=b.z; Ys[kc*4+3][r]=b.w;
    Vs[kc*4+0][r]=c.x; Vs[kc*4+1][r]=c.y; Vs[kc*4+2][r]=c.z; Vs[kc*4+3][r]=c.w;
  }
  __syncthreads();
#pragma unroll
  for (int kk = 0; kk < GD; ++kk) {
    float4 ax = *reinterpret_cast<const float4*>(&Xs[kk][ty * 4]);
    float4 ay = *reinterpret_cast<const float4*>(&Ys[kk][ty * 4]);
    float4 bv = *reinterpret_cast<const float4*>(&Vs[kk][tx * 4]);
    float axv[4] = {ax.x, ax.y, ax.z, ax.w};
    float ayv[4] = {ay.x, ay.y, ay.z, ay.w};
    float bvv[4] = {bv.x, bv.y, bv.z, bv.w};
#pragma unroll
    for (int i = 0; i < 4; ++i)
#pragma unroll
      for (int j = 0; j < 4; ++j) {
        Sxg[i][j] = fmaf(axv[i], bvv[j], Sxg[i][j]);
        Syg[i][j] = fmaf(ayv[i], bvv[j], Syg[i][j]);
      }
  }

  // epilogue: kernels, fm, partial reductions
  float ep  = 1.f / (1.f + __expf(-p_eps[0]));
  float sg  = p_sig[0] * p_sig[0];
  float sg0 = p_sig0[0] * p_sig0[0];
  float cst = p_cst[0];
  float nis = -1.f / sg, nis0 = -1.f / sg0;
  float omep = 1.f - ep;
  float ss = 0.f;
  float colp[4] = {0.f, 0.f, 0.f, 0.f};
#pragma unroll
  for (int i = 0; i < 4; ++i) {
    float vout[4];
    float fx = fnX[ty*4+i], fy = fnY[ty*4+i];
    float gx = gnX[ty*4+i], gy = gnY[ty*4+i];
#pragma unroll
    for (int j = 0; j < 4; ++j) {
      float fv = fnV[tx*4+j], gv = gnV[tx*4+j];
      float dxf = fmaxf(fx + fv - 2.f * Sxf[i][j], 0.f);
      float dxg = fmaxf(gx + gv - 2.f * Sxg[i][j], 0.f);
      float dyf = fmaxf(fy + fv - 2.f * Syf[i][j], 0.f);
      float dyg = fmaxf(gy + gv - 2.f * Syg[i][j], 0.f);
      float kx = cst * (omep * __expf(dxf * nis0) + ep) * __expf(dxg * nis);
      float ky = cst * (omep * __expf(dyf * nis0) + ep) * __expf(dyg * nis);
      float fmv = (kx - ky) * 0.03125f;  // /sqrt(1024)
      vout[j] = fmv;
      ss = fmaf(fmv, fmv, ss);
      colp[j] += fmv;
    }
    *reinterpret_cast<float4*>(&fm[(size_t)(i0 + ty * 4 + i) * NV + j0 + tx * 4]) =
        make_float4(vout[0], vout[1], vout[2], vout[3]);
  }
#pragma unroll
  for (int m = 32; m >= 1; m >>= 1) ss += __shfl_xor(ss, m);
  if ((tid & 63) == 0) ssred[tid >> 6] = ss;
#pragma unroll
  for (int j = 0; j < 4; ++j) red[ty][tx * 4 + j] = colp[j];
  __syncthreads();
  if (tid < 64) {
    float s = 0.f;
#pragma unroll
    for (int t = 0; t < 16; ++t) s += red[t][tid];
    atomicAdd(&colsum[j0 + tid], (double)s);
  }
  if (tid == 0) {
    double v = (double)ssred[0] + ssred[1] + ssred[2] + ssred[3];
    atomicAdd(&ss_parts[blockIdx.x & 63], v);
  }
}

// ---------------------------------------------------------------------------
// mu_j = colsum_j / nx (fp32 for pass2) ; summu2 = sum mu^2 (double)
// ---------------------------------------------------------------------------
__global__ __launch_bounds__(256) void mu_k(
    const double* __restrict__ colsum, float* __restrict__ mu,
    double* __restrict__ summu2)
{
  __shared__ double wred[4];
  double local = 0.0;
  for (int j = threadIdx.x; j < NV; j += 256) {
    double m = colsum[j] * (1.0 / (double)NXP);
    mu[j] = (float)m;
    local += m * m;
  }
  int lane = threadIdx.x & 63, wave = threadIdx.x >> 6;
#pragma unroll
  for (int m = 32; m >= 1; m >>= 1) local += __shfl_xor(local, m);
  if (lane == 0) wred[wave] = local;
  __syncthreads();
  if (threadIdx.x == 0) *summu2 = wred[0] + wred[1] + wred[2] + wred[3];
}

// ---------------------------------------------------------------------------
// Pass 2: z_i = fm[i,:] . mu ; accumulate sum z^2 (double atomics, 64 slots)
// One wave per row, 4 rows per block.
// ---------------------------------------------------------------------------
__global__ __launch_bounds__(256) void pass2_k(
    const float* __restrict__ fm, const float* __restrict__ mu,
    double* __restrict__ sz_parts)
{
  __shared__ float4 mus[NV / 4];
  for (int l = threadIdx.x; l < NV / 4; l += 256)
    mus[l] = reinterpret_cast<const float4*>(mu)[l];
  __syncthreads();
  __shared__ double zb[4];
  int wave = threadIdx.x >> 6, lane = threadIdx.x & 63;
  int row = blockIdx.x * 4 + wave;
  const float4* frow = reinterpret_cast<const float4*>(fm + (size_t)row * NV);
  float z = 0.f;
#pragma unroll
  for (int it = 0; it < 4; ++it) {
    float4 f = frow[lane + 64 * it];
    float4 m = mus[lane + 64 * it];
    z = fmaf(f.x, m.x, z); z = fmaf(f.y, m.y, z);
    z = fmaf(f.z, m.z, z); z = fmaf(f.w, m.w, z);
  }
#pragma unroll
  for (int m = 32; m >= 1; m >>= 1) z += __shfl_xor(z, m);
  if (lane == 0) zb[wave] = (double)z * (double)z;
  __syncthreads();
  if (threadIdx.x == 0)
    atomicAdd(&sz_parts[blockIdx.x & 63], zb[0] + zb[1] + zb[2] + zb[3]);
}

// ---------------------------------------------------------------------------
// Final scalar
// ---------------------------------------------------------------------------
__global__ __launch_bounds__(64) void final_k(
    const double* __restrict__ ss_parts, const double* __restrict__ sz_parts,
    const double* __restrict__ summu2, float* __restrict__ out)
{
  int lane = threadIdx.x;
  double ss = ss_parts[lane], sz = sz_parts[lane];
#pragma unroll
  for (int m = 32; m >= 1; m >>= 1) { ss += __shfl_xor(ss, m); sz += __shfl_xor(sz, m); }
  if (lane == 0) {
    double smu2 = *summu2;
    const double nx = (double)NXP;
    double t1 = smu2 * nx / (nx - 1.0);
    double t2 = ss / (nx * (nx - 1.0));
    double um = t1 - t2;
    double uv = 4.0 * (sz / nx) - 4.0 * smu2 * smu2;
    out[0] = (float)(-(um / sqrt(uv + 1e-6)));
  }
}

// ---------------------------------------------------------------------------
extern "C" void kernel_launch(void* const* d_in, const int* in_sizes, int n_in,
                              void* d_out, int out_size, void* d_ws, size_t ws_size,
                              hipStream_t stream)
{
  (void)in_sizes; (void)n_in; (void)out_size; (void)ws_size;
  const float* XY = (const float*)d_in[0];
  const float* V  = (const float*)d_in[1];
  const float* dnW[6]; const float* dnb[6]; const float* anW[6]; const float* anb[6];
  for (int i = 0; i < 6; ++i) {
    dnW[i] = (const float*)d_in[2 + 2 * i];  dnb[i] = (const float*)d_in[3 + 2 * i];
    anW[i] = (const float*)d_in[14 + 2 * i]; anb[i] = (const float*)d_in[15 + 2 * i];
  }
  const float* p_eps  = (const float*)d_in[26];
  const float* p_sig  = (const float*)d_in[27];
  const float* p_sig0 = (const float*)d_in[28];
  const float* p_cst  = (const float*)d_in[29];

  char* base = (char*)d_ws;
  size_t off = 0;
  auto alloc = [&](size_t b) { size_t o = off; off += (b + 255) & ~(size_t)255; return o; };
  float*  Xin   = (float*) (base + alloc((size_t)NROW * GD * 4));
  float*  f_all = (float*) (base + alloc((size_t)NROW * FD * 4));
  float*  g_all = (float*) (base + alloc((size_t)NROW * GD * 4));
  float*  fn    = (float*) (base + alloc((size_t)NROW * 4));
  float*  gn    = (float*) (base + alloc((size_t)NROW * 4));
  float*  mu    = (float*) (base + alloc((size_t)NV * 4));
  size_t zoff = off;
  double* colsum   = (double*)(base + alloc(NV * 8));
  double* ss_parts = (double*)(base + alloc(64 * 8));
  double* sz_parts = (double*)(base + alloc(64 * 8));
  double* summu2   = (double*)(base + alloc(8));
  size_t zbytes = off - zoff;
  float* h1 = (float*)(base + alloc((size_t)NROW * HD * 4));
  float* h2 = (float*)(base + alloc((size_t)NROW * HD * 4));
  float* fm = h1;  // overlay: 32768*1024*4 = 134.2MB <= h1+h2 (159.7MB)

  hipMemsetAsync(base + zoff, 0, zbytes, stream);
  hipMemcpyAsync(Xin, XY, (size_t)2 * NXP * GD * 4, hipMemcpyDeviceToDevice, stream);
  hipMemcpyAsync(Xin + (size_t)2 * NXP * GD, V, (size_t)NV * GD * 4,
                 hipMemcpyDeviceToDevice, stream);

  dim3 blk(256);
  const int GR = NROW / 128;  // 520 row tiles
  // dn MLP -> f_all
  gemm_k<true,  false><<<dim3(GR, 5), blk, 0, stream>>>(Xin, dnW[0], dnb[0], nullptr, h1, NROW, GD, HD);
  gemm_k<true,  false><<<dim3(GR, 5), blk, 0, stream>>>(h1,  dnW[1], dnb[1], nullptr, h2, NROW, HD, HD);
  gemm_k<true,  false><<<dim3(GR, 5), blk, 0, stream>>>(h2,  dnW[2], dnb[2], nullptr, h1, NROW, HD, HD);
  gemm_k<true,  false><<<dim3(GR, 5), blk, 0, stream>>>(h1,  dnW[3], dnb[3], nullptr, h2, NROW, HD, HD);
  gemm_k<true,  false><<<dim3(GR, 5), blk, 0, stream>>>(h2,  dnW[4], dnb[4], nullptr, h1, NROW, HD, HD);
  gemm_k<false, false><<<dim3(GR, 2), blk, 0, stream>>>(h1,  dnW[5], dnb[5], nullptr, f_all, NROW, HD, FD);
  // an MLP (+x residual) -> g_all
  gemm_k<true,  false><<<dim3(GR, 5), blk, 0, stream>>>(Xin, anW[0], anb[0], nullptr, h1, NROW, GD, HD);
  gemm_k<true,  false><<<dim3(GR, 5), blk, 0, stream>>>(h1,  anW[1], anb[1], nullptr, h2, NROW, HD, HD);
  gemm_k<true,  false><<<dim3(GR, 5), blk, 0, stream>>>(h2,  anW[2], anb[2], nullptr, h1, NROW, HD, HD);
  gemm_k<true,  false><<<dim3(GR, 5), blk, 0, stream>>>(h1,  anW[3], anb[3], nullptr, h2, NROW, HD, HD);
  gemm_k<true,  false><<<dim3(GR, 5), blk, 0, stream>>>(h2,  anW[4], anb[4], nullptr, h1, NROW, HD, HD);
  gemm_k<false, true ><<<dim3(GR, 1), blk, 0, stream>>>(h1,  anW[5], anb[5], Xin, g_all, NROW, HD, GD);

  norms_k<<<NROW / 4, blk, 0, stream>>>(f_all, g_all, fn, gn);
  dist1_k<<<dim3(NXP / 64, NV / 64), blk, 0, stream>>>(
      f_all, g_all, fn, gn, p_eps, p_sig, p_sig0, p_cst, fm, colsum, ss_parts);
  mu_k<<<1, blk, 0, stream>>>(colsum, mu, summu2);
  pass2_k<<<NXP / 4, blk, 0, stream>>>(fm, mu, sz_parts);
  final_k<<<1, 64, 0, stream>>>(ss_parts, sz_parts, summu2, (float*)d_out);
}

// Round 2
// 1377.228 us; speedup vs baseline: 1.4105x; 1.4105x over previous
//
#include <hip/hip_runtime.h>
#include <cstdint>

#define NROW 66560   // 2*NX + J rows through both MLPs
#define NXP  32768   // nx
#define NV   1024    // J
#define FD   100     // dn output dim
#define GD   28      // input / an output dim
#define HD   300     // hidden dim
#define HP   320     // padded hidden dim (k-padding for BK=32)

typedef unsigned short u16;
typedef __bf16 bf16x8 __attribute__((ext_vector_type(8)));
typedef float  f32x4  __attribute__((ext_vector_type(4)));

__device__ inline u16 f2bf(float x) {
  unsigned u = __builtin_bit_cast(unsigned, x);
  unsigned r = (u + 0x7FFF + ((u >> 16) & 1)) >> 16;
  return (u16)r;
}
__device__ inline float bf2f(u16 h) {
  unsigned u = ((unsigned)h) << 16;
  return __builtin_bit_cast(float, u);
}

// ---------------------------------------------------------------------------
// Prep: assemble [X;Y;V] rows, emit bf16 hi/lo planes (K padded 28->32) and
// fp32 copy (for the an-MLP residual).
// ---------------------------------------------------------------------------
__global__ __launch_bounds__(256) void prep_x(
    const float* __restrict__ XY, const float* __restrict__ V,
    u16* __restrict__ Xhi, u16* __restrict__ Xlo, float* __restrict__ Xf)
{
  int gid = blockIdx.x * 256 + threadIdx.x;   // NROW*32 total
  int row = gid >> 5, k = gid & 31;
  if (row >= NROW) return;
  float v = 0.f;
  if (k < GD) v = (row < 2 * NXP) ? XY[(size_t)row * GD + k]
                                  : V[(size_t)(row - 2 * NXP) * GD + k];
  u16 hi = f2bf(v);
  u16 lo = f2bf(v - bf2f(hi));
  Xhi[(size_t)row * 32 + k] = hi;
  Xlo[(size_t)row * 32 + k] = lo;
  if (k < GD) Xf[(size_t)row * GD + k] = v;
}

// ---------------------------------------------------------------------------
// Prep: transpose + split + zero-pad all 12 weight matrices.
// Wt[m][k] layout (B-operand wants [n][k] with contiguous k).
// ---------------------------------------------------------------------------
struct WDesc { const float* W; u16* hi; u16* lo; int K, M, Kpad, Mpad; };
struct WAll  { WDesc d[12]; };

__global__ __launch_bounds__(256) void prep_w(WAll wa)
{
  WDesc d = wa.d[blockIdx.y];
  int gid = blockIdx.x * 256 + threadIdx.x;
  if (gid >= d.Kpad * d.Mpad) return;
  int m = gid / d.Kpad, k = gid - m * d.Kpad;
  float v = (k < d.K && m < d.M) ? d.W[(size_t)k * d.M + m] : 0.f;
  u16 hi = f2bf(v);
  u16 lo = f2bf(v - bf2f(hi));
  d.hi[(size_t)m * d.Kpad + k] = hi;
  d.lo[(size_t)m * d.Kpad + k] = lo;
}

// ---------------------------------------------------------------------------
// Split-bf16 MFMA GEMM: C = act(A @ W^T(stored) + bias [+ resid])
// A: hi/lo bf16 planes [N][sA]; B: Wt hi/lo [Mpad][sB]; 3 MFMAs per product.
// BM=128, BN=64, BK=32; 128 threads = 2 waves, each wave a 64x64 tile
// of 4x4 16x16x32 MFMAs. LDS stride 40 bf16 (80B) -> free 2-way aliasing.
// SPLIT: write hi/lo bf16 planes (stride sC, k-pad zeros come out naturally);
// else: write fp32 [N][Mreal] with col guard (+ optional residual).
// ---------------------------------------------------------------------------
template<bool RELU, bool RESID, bool SPLIT>
__global__ __launch_bounds__(128) void gemm_mfma(
    const u16* __restrict__ Ahi, const u16* __restrict__ Alo, int sA,
    const u16* __restrict__ Bhi, const u16* __restrict__ Blo, int sB,
    const float* __restrict__ bias, const float* __restrict__ resid,
    u16* __restrict__ Chi, u16* __restrict__ Clo, int sC,
    float* __restrict__ Cf, int Mreal, int Kch)
{
  __shared__ u16 AsH[128 * 40], AsL[128 * 40], BsH[64 * 40], BsL[64 * 40];
  const int tid  = threadIdx.x;
  const int lane = tid & 63, wave = tid >> 6;
  const int m16  = lane & 15, quad = lane >> 4;
  const int row0 = blockIdx.x * 128;
  const int col0 = blockIdx.y * 64;

  f32x4 acc[4][4];
#pragma unroll
  for (int i = 0; i < 4; ++i)
#pragma unroll
    for (int j = 0; j < 4; ++j) acc[i][j] = (f32x4)0.f;

  for (int ch = 0; ch < Kch; ++ch) {
    const int k0 = ch * 32;
    __syncthreads();
    // stage A tiles (hi+lo): 512 16B-chunks per plane, 4/thread
#pragma unroll
    for (int i = 0; i < 4; ++i) {
      int id = tid + i * 128;
      int r = id >> 2, kc = id & 3;
      uint4 h = *reinterpret_cast<const uint4*>(&Ahi[(size_t)(row0 + r) * sA + k0 + kc * 8]);
      uint4 l = *reinterpret_cast<const uint4*>(&Alo[(size_t)(row0 + r) * sA + k0 + kc * 8]);
      *reinterpret_cast<uint4*>(&AsH[r * 40 + kc * 8]) = h;
      *reinterpret_cast<uint4*>(&AsL[r * 40 + kc * 8]) = l;
    }
    // stage B tiles (hi+lo): 256 chunks per plane, 2/thread
#pragma unroll
    for (int i = 0; i < 2; ++i) {
      int id = tid + i * 128;
      int r = id >> 2, kc = id & 3;
      uint4 h = *reinterpret_cast<const uint4*>(&Bhi[(size_t)(col0 + r) * sB + k0 + kc * 8]);
      uint4 l = *reinterpret_cast<const uint4*>(&Blo[(size_t)(col0 + r) * sB + k0 + kc * 8]);
      *reinterpret_cast<uint4*>(&BsH[r * 40 + kc * 8]) = h;
      *reinterpret_cast<uint4*>(&BsL[r * 40 + kc * 8]) = l;
    }
    __syncthreads();

    bf16x8 ah[4], al[4], bh[4], bl[4];
#pragma unroll
    for (int i = 0; i < 4; ++i) {
      int off = (wave * 64 + i * 16 + m16) * 40 + quad * 8;
      ah[i] = *reinterpret_cast<const bf16x8*>(&AsH[off]);
      al[i] = *reinterpret_cast<const bf16x8*>(&AsL[off]);
    }
#pragma unroll
    for (int j = 0; j < 4; ++j) {
      int off = (j * 16 + m16) * 40 + quad * 8;
      bh[j] = *reinterpret_cast<const bf16x8*>(&BsH[off]);
      bl[j] = *reinterpret_cast<const bf16x8*>(&BsL[off]);
    }
#pragma unroll
    for (int i = 0; i < 4; ++i)
#pragma unroll
      for (int j = 0; j < 4; ++j) {
        acc[i][j] = __builtin_amdgcn_mfma_f32_16x16x32_bf16(ah[i], bh[j], acc[i][j], 0, 0, 0);
        acc[i][j] = __builtin_amdgcn_mfma_f32_16x16x32_bf16(ah[i], bl[j], acc[i][j], 0, 0, 0);
        acc[i][j] = __builtin_amdgcn_mfma_f32_16x16x32_bf16(al[i], bh[j], acc[i][j], 0, 0, 0);
      }
  }

  // epilogue: C/D layout col=lane&15, row=quad*4+reg (m89-verified)
#pragma unroll
  for (int j = 0; j < 4; ++j) {
    int col = col0 + j * 16 + m16;
    float bv = (col < Mreal) ? bias[col] : 0.f;
#pragma unroll
    for (int i = 0; i < 4; ++i) {
#pragma unroll
      for (int r = 0; r < 4; ++r) {
        int row = row0 + wave * 64 + i * 16 + quad * 4 + r;
        float x = acc[i][j][r] + bv;
        if (RELU) x = fmaxf(x, 0.f);
        if (SPLIT) {
          u16 hi = f2bf(x);
          u16 lo = f2bf(x - bf2f(hi));
          Chi[(size_t)row * sC + col] = hi;
          Clo[(size_t)row * sC + col] = lo;
        } else if (col < Mreal) {
          if (RESID) x += resid[(size_t)row * Mreal + col];
          Cf[(size_t)row * Mreal + col] = x;
        }
      }
    }
  }
}

// ---------------------------------------------------------------------------
// Row squared-norms of f_all (100 dims) and g_all (28 dims). One wave per row.
// ---------------------------------------------------------------------------
__global__ __launch_bounds__(256) void norms_k(
    const float* __restrict__ f_all, const float* __restrict__ g_all,
    float* __restrict__ fn, float* __restrict__ gn)
{
  int wave = threadIdx.x >> 6, lane = threadIdx.x & 63;
  int row = blockIdx.x * 4 + wave;
  const float* f = f_all + (size_t)row * FD;
  const float* g = g_all + (size_t)row * GD;
  float s = f[lane] * f[lane];
  if (lane < FD - 64) { float t = f[lane + 64]; s += t * t; }
  float sg = 0.f;
  if (lane < GD) { float t = g[lane]; sg = t * t; }
#pragma unroll
  for (int m = 32; m >= 1; m >>= 1) { s += __shfl_xor(s, m); sg += __shfl_xor(sg, m); }
  if (lane == 0) { fn[row] = s; gn[row] = sg; }
}

// ---------------------------------------------------------------------------
// Pass 1: fused pdist2 + kernel + fm write + colsum/ss partial reductions.
// ---------------------------------------------------------------------------
__global__ __launch_bounds__(256) void dist1_k(
    const float* __restrict__ f_all, const float* __restrict__ g_all,
    const float* __restrict__ fn, const float* __restrict__ gn,
    const float* __restrict__ p_eps, const float* __restrict__ p_sig,
    const float* __restrict__ p_sig0, const float* __restrict__ p_cst,
    float* __restrict__ fm, double* __restrict__ colsum,
    double* __restrict__ ss_parts)
{
  __shared__ float Xs[GD][68], Ys[GD][68], Vs[GD][68];  // f-phase uses rows 0..19
  __shared__ float fnX[64], fnY[64], fnV[64], gnX[64], gnY[64], gnV[64];
  __shared__ float red[16][68];
  __shared__ float ssred[4];
  const int tid = threadIdx.x;
  const int tx = tid & 15, ty = tid >> 4;
  const int i0 = blockIdx.x * 64, j0 = blockIdx.y * 64;

  if (tid < 64) {
    fnX[tid] = fn[i0 + tid]; fnY[tid] = fn[NXP + i0 + tid]; fnV[tid] = fn[2 * NXP + j0 + tid];
    gnX[tid] = gn[i0 + tid]; gnY[tid] = gn[NXP + i0 + tid]; gnV[tid] = gn[2 * NXP + j0 + tid];
  }

  float Sxf[4][4] = {}, Syf[4][4] = {}, Sxg[4][4] = {}, Syg[4][4] = {};
  const float* fX = f_all;
  const float* fY = f_all + (size_t)NXP * FD;
  const float* fV = f_all + (size_t)2 * NXP * FD;
  const float* gX = g_all;
  const float* gY = g_all + (size_t)NXP * GD;
  const float* gV = g_all + (size_t)2 * NXP * GD;

  for (int k0 = 0; k0 < FD; k0 += 20) {
    __syncthreads();
    for (int l = tid; l < 320; l += 256) {
      int r = l / 5, kc = l % 5;
      float4 a = *reinterpret_cast<const float4*>(&fX[(size_t)(i0 + r) * FD + k0 + kc * 4]);
      float4 b = *reinterpret_cast<const float4*>(&fY[(size_t)(i0 + r) * FD + k0 + kc * 4]);
      float4 c = *reinterpret_cast<const float4*>(&fV[(size_t)(j0 + r) * FD + k0 + kc * 4]);
      Xs[kc*4+0][r]=a.x; Xs[kc*4+1][r]=a.y; Xs[kc*4+2][r]=a.z; Xs[kc*4+3][r]=a.w;
      Ys[kc*4+0][r]=b.x; Ys[kc*4+1][r]=b.y; Ys[kc*4+2][r]=b.z; Ys[kc*4+3][r]=b.w;
      Vs[kc*4+0][r]=c.x; Vs[kc*4+1][r]=c.y; Vs[kc*4+2][r]=c.z; Vs[kc*4+3][r]=c.w;
    }
    __syncthreads();
#pragma unroll
    for (int kk = 0; kk < 20; ++kk) {
      float4 ax = *reinterpret_cast<const float4*>(&Xs[kk][ty * 4]);
      float4 ay = *reinterpret_cast<const float4*>(&Ys[kk][ty * 4]);
      float4 bv = *reinterpret_cast<const float4*>(&Vs[kk][tx * 4]);
      float axv[4] = {ax.x, ax.y, ax.z, ax.w};
      float ayv[4] = {ay.x, ay.y, ay.z, ay.w};
      float bvv[4] = {bv.x, bv.y, bv.z, bv.w};
#pragma unroll
      for (int i = 0; i < 4; ++i)
#pragma unroll
        for (int j = 0; j < 4; ++j) {
          Sxf[i][j] = fmaf(axv[i], bvv[j], Sxf[i][j]);
          Syf[i][j] = fmaf(ayv[i], bvv[j], Syf[i][j]);
        }
    }
  }

  __syncthreads();
  for (int l = tid; l < 448; l += 256) {
    int r = l / 7, kc = l % 7;
    float4 a = *reinterpret_cast<const float4*>(&gX[(size_t)(i0 + r) * GD + kc * 4]);
    float4 b = *reinterpret_cast<const float4*>(&gY[(size_t)(i0 + r) * GD + kc * 4]);
    float4 c = *reinterpret_cast<const float4*>(&gV[(size_t)(j0 + r) * GD + kc * 4]);
    Xs[kc*4+0][r]=a.x; Xs[kc*4+1][r]=a.y; Xs[kc*4+2][r]=a.z; Xs[kc*4+3][r]=a.w;
    Ys[kc*4+0][r]=b.x; Ys[kc*4+1][r]=b.y; Ys[kc*4+2][r]=b.z; Ys[kc*4+3][r]=b.w;
    Vs[kc*4+0][r]=c.x; Vs[kc*4+1][r]=c.y; Vs[kc*4+2][r]=c.z; Vs[kc*4+3][r]=c.w;
  }
  __syncthreads();
#pragma unroll
  for (int kk = 0; kk < GD; ++kk) {
    float4 ax = *reinterpret_cast<const float4*>(&Xs[kk][ty * 4]);
    float4 ay = *reinterpret_cast<const float4*>(&Ys[kk][ty * 4]);
    float4 bv = *reinterpret_cast<const float4*>(&Vs[kk][tx * 4]);
    float axv[4] = {ax.x, ax.y, ax.z, ax.w};
    float ayv[4] = {ay.x, ay.y, ay.z, ay.w};
    float bvv[4] = {bv.x, bv.y, bv.z, bv.w};
#pragma unroll
    for (int i = 0; i < 4; ++i)
#pragma unroll
      for (int j = 0; j < 4; ++j) {
        Sxg[i][j] = fmaf(axv[i], bvv[j], Sxg[i][j]);
        Syg[i][j] = fmaf(ayv[i], bvv[j], Syg[i][j]);
      }
  }

  float ep  = 1.f / (1.f + __expf(-p_eps[0]));
  float sg  = p_sig[0] * p_sig[0];
  float sg0 = p_sig0[0] * p_sig0[0];
  float cst = p_cst[0];
  float nis = -1.f / sg, nis0 = -1.f / sg0;
  float omep = 1.f - ep;
  float ss = 0.f;
  float colp[4] = {0.f, 0.f, 0.f, 0.f};
#pragma unroll
  for (int i = 0; i < 4; ++i) {
    float vout[4];
    float fx = fnX[ty*4+i], fy = fnY[ty*4+i];
    float gx = gnX[ty*4+i], gy = gnY[ty*4+i];
#pragma unroll
    for (int j = 0; j < 4; ++j) {
      float fv = fnV[tx*4+j], gv = gnV[tx*4+j];
      float dxf = fmaxf(fx + fv - 2.f * Sxf[i][j], 0.f);
      float dxg = fmaxf(gx + gv - 2.f * Sxg[i][j], 0.f);
      float dyf = fmaxf(fy + fv - 2.f * Syf[i][j], 0.f);
      float dyg = fmaxf(gy + gv - 2.f * Syg[i][j], 0.f);
      float kx = cst * (omep * __expf(dxf * nis0) + ep) * __expf(dxg * nis);
      float ky = cst * (omep * __expf(dyf * nis0) + ep) * __expf(dyg * nis);
      float fmv = (kx - ky) * 0.03125f;
      vout[j] = fmv;
      ss = fmaf(fmv, fmv, ss);
      colp[j] += fmv;
    }
    *reinterpret_cast<float4*>(&fm[(size_t)(i0 + ty * 4 + i) * NV + j0 + tx * 4]) =
        make_float4(vout[0], vout[1], vout[2], vout[3]);
  }
#pragma unroll
  for (int m = 32; m >= 1; m >>= 1) ss += __shfl_xor(ss, m);
  if ((tid & 63) == 0) ssred[tid >> 6] = ss;
#pragma unroll
  for (int j = 0; j < 4; ++j) red[ty][tx * 4 + j] = colp[j];
  __syncthreads();
  if (tid < 64) {
    float s = 0.f;
#pragma unroll
    for (int t = 0; t < 16; ++t) s += red[t][tid];
    atomicAdd(&colsum[j0 + tid], (double)s);
  }
  if (tid == 0) {
    double v = (double)ssred[0] + ssred[1] + ssred[2] + ssred[3];
    atomicAdd(&ss_parts[blockIdx.x & 63], v);
  }
}

__global__ __launch_bounds__(256) void mu_k(
    const double* __restrict__ colsum, float* __restrict__ mu,
    double* __restrict__ summu2)
{
  __shared__ double wred[4];
  double local = 0.0;
  for (int j = threadIdx.x; j < NV; j += 256) {
    double m = colsum[j] * (1.0 / (double)NXP);
    mu[j] = (float)m;
    local += m * m;
  }
  int lane = threadIdx.x & 63, wave = threadIdx.x >> 6;
#pragma unroll
  for (int m = 32; m >= 1; m >>= 1) local += __shfl_xor(local, m);
  if (lane == 0) wred[wave] = local;
  __syncthreads();
  if (threadIdx.x == 0) *summu2 = wred[0] + wred[1] + wred[2] + wred[3];
}

__global__ __launch_bounds__(256) void pass2_k(
    const float* __restrict__ fm, const float* __restrict__ mu,
    double* __restrict__ sz_parts)
{
  __shared__ float4 mus[NV / 4];
  for (int l = threadIdx.x; l < NV / 4; l += 256)
    mus[l] = reinterpret_cast<const float4*>(mu)[l];
  __syncthreads();
  __shared__ double zb[4];
  int wave = threadIdx.x >> 6, lane = threadIdx.x & 63;
  int row = blockIdx.x * 4 + wave;
  const float4* frow = reinterpret_cast<const float4*>(fm + (size_t)row * NV);
  float z = 0.f;
#pragma unroll
  for (int it = 0; it < 4; ++it) {
    float4 f = frow[lane + 64 * it];
    float4 m = mus[lane + 64 * it];
    z = fmaf(f.x, m.x, z); z = fmaf(f.y, m.y, z);
    z = fmaf(f.z, m.z, z); z = fmaf(f.w, m.w, z);
  }
#pragma unroll
  for (int m = 32; m >= 1; m >>= 1) z += __shfl_xor(z, m);
  if (lane == 0) zb[wave] = (double)z * (double)z;
  __syncthreads();
  if (threadIdx.x == 0)
    atomicAdd(&sz_parts[blockIdx.x & 63], zb[0] + zb[1] + zb[2] + zb[3]);
}

__global__ __launch_bounds__(64) void final_k(
    const double* __restrict__ ss_parts, const double* __restrict__ sz_parts,
    const double* __restrict__ summu2, float* __restrict__ out)
{
  int lane = threadIdx.x;
  double ss = ss_parts[lane], sz = sz_parts[lane];
#pragma unroll
  for (int m = 32; m >= 1; m >>= 1) { ss += __shfl_xor(ss, m); sz += __shfl_xor(sz, m); }
  if (lane == 0) {
    double smu2 = *summu2;
    const double nx = (double)NXP;
    double t1 = smu2 * nx / (nx - 1.0);
    double t2 = ss / (nx * (nx - 1.0));
    double um = t1 - t2;
    double uv = 4.0 * (sz / nx) - 4.0 * smu2 * smu2;
    out[0] = (float)(-(um / sqrt(uv + 1e-6)));
  }
}

// ---------------------------------------------------------------------------
extern "C" void kernel_launch(void* const* d_in, const int* in_sizes, int n_in,
                              void* d_out, int out_size, void* d_ws, size_t ws_size,
                              hipStream_t stream)
{
  (void)in_sizes; (void)n_in; (void)out_size; (void)ws_size;
  const float* XY = (const float*)d_in[0];
  const float* V  = (const float*)d_in[1];
  const float* dnW[6]; const float* dnb[6]; const float* anW[6]; const float* anb[6];
  for (int i = 0; i < 6; ++i) {
    dnW[i] = (const float*)d_in[2 + 2 * i];  dnb[i] = (const float*)d_in[3 + 2 * i];
    anW[i] = (const float*)d_in[14 + 2 * i]; anb[i] = (const float*)d_in[15 + 2 * i];
  }
  const float* p_eps  = (const float*)d_in[26];
  const float* p_sig  = (const float*)d_in[27];
  const float* p_sig0 = (const float*)d_in[28];
  const float* p_cst  = (const float*)d_in[29];

  char* base = (char*)d_ws;
  size_t off = 0;
  auto alloc = [&](size_t b) { size_t o = off; off += (b + 255) & ~(size_t)255; return o; };
  float* Xf    = (float*)(base + alloc((size_t)NROW * GD * 4));
  u16*   Xhi   = (u16*)  (base + alloc((size_t)NROW * 32 * 2));
  u16*   Xlo   = (u16*)  (base + alloc((size_t)NROW * 32 * 2));
  float* f_all = (float*)(base + alloc((size_t)NROW * FD * 4));
  float* g_all = (float*)(base + alloc((size_t)NROW * GD * 4));
  float* fn    = (float*)(base + alloc((size_t)NROW * 4));
  float* gn    = (float*)(base + alloc((size_t)NROW * 4));
  float* mu    = (float*)(base + alloc((size_t)NV * 4));
  size_t zoff = off;
  double* colsum   = (double*)(base + alloc(NV * 8));
  double* ss_parts = (double*)(base + alloc(64 * 8));
  double* sz_parts = (double*)(base + alloc(64 * 8));
  double* summu2   = (double*)(base + alloc(8));
  size_t zbytes = off - zoff;
  // weight slots: uniform 320x320 per layer per plane
  u16* Whi = (u16*)(base + alloc((size_t)12 * HP * HP * 2));
  u16* Wlo = (u16*)(base + alloc((size_t)12 * HP * HP * 2));
  // hidden activation ping-pong (hi/lo planes), contiguous region
  u16* H1h = (u16*)(base + alloc((size_t)NROW * HP * 2));
  u16* H1l = (u16*)(base + alloc((size_t)NROW * HP * 2));
  u16* H2h = (u16*)(base + alloc((size_t)NROW * HP * 2));
  u16* H2l = (u16*)(base + alloc((size_t)NROW * HP * 2));
  float* fm = (float*)H1h;  // overlay: 134.2 MB <= 4 x 42.6 MB contiguous

  hipMemsetAsync(base + zoff, 0, zbytes, stream);

  dim3 blk(256);
  prep_x<<<NROW * 32 / 256, blk, 0, stream>>>(XY, V, Xhi, Xlo, Xf);

  WAll wa;
  auto wslot = [&](int s, u16** hi, u16** lo) {
    *hi = Whi + (size_t)s * HP * HP; *lo = Wlo + (size_t)s * HP * HP;
  };
  for (int i = 0; i < 6; ++i) {
    u16 *hi, *lo; wslot(i, &hi, &lo);
    int K = (i == 0) ? GD : HD, M = (i == 5) ? FD : HD;
    int Kp = (i == 0) ? 32 : HP, Mp = (i == 5) ? 128 : HP;
    wa.d[i] = {dnW[i], hi, lo, K, M, Kp, Mp};
  }
  for (int i = 0; i < 6; ++i) {
    u16 *hi, *lo; wslot(6 + i, &hi, &lo);
    int K = (i == 0) ? GD : HD, M = (i == 5) ? GD : HD;
    int Kp = (i == 0) ? 32 : HP, Mp = (i == 5) ? 64 : HP;
    wa.d[6 + i] = {anW[i], hi, lo, K, M, Kp, Mp};
  }
  prep_w<<<dim3((HP * HP + 255) / 256, 12), blk, 0, stream>>>(wa);

  const int GR = NROW / 128;  // 520 row blocks
  dim3 gblk(128);
  auto W = [&](int s) { return Whi + (size_t)s * HP * HP; };
  auto L = [&](int s) { return Wlo + (size_t)s * HP * HP; };

  // dn MLP -> f_all
  gemm_mfma<true,  false, true ><<<dim3(GR, 5), gblk, 0, stream>>>(
      Xhi, Xlo, 32, W(0), L(0), 32, dnb[0], nullptr, H1h, H1l, HP, nullptr, HD, 1);
  gemm_mfma<true,  false, true ><<<dim3(GR, 5), gblk, 0, stream>>>(
      H1h, H1l, HP, W(1), L(1), HP, dnb[1], nullptr, H2h, H2l, HP, nullptr, HD, 10);
  gemm_mfma<true,  false, true ><<<dim3(GR, 5), gblk, 0, stream>>>(
      H2h, H2l, HP, W(2), L(2), HP, dnb[2], nullptr, H1h, H1l, HP, nullptr, HD, 10);
  gemm_mfma<true,  false, true ><<<dim3(GR, 5), gblk, 0, stream>>>(
      H1h, H1l, HP, W(3), L(3), HP, dnb[3], nullptr, H2h, H2l, HP, nullptr, HD, 10);
  gemm_mfma<true,  false, true ><<<dim3(GR, 5), gblk, 0, stream>>>(
      H2h, H2l, HP, W(4), L(4), HP, dnb[4], nullptr, H1h, H1l, HP, nullptr, HD, 10);
  gemm_mfma<false, false, false><<<dim3(GR, 2), gblk, 0, stream>>>(
      H1h, H1l, HP, W(5), L(5), HP, dnb[5], nullptr, nullptr, nullptr, 0, f_all, FD, 10);
  // an MLP (+x residual) -> g_all
  gemm_mfma<true,  false, true ><<<dim3(GR, 5), gblk, 0, stream>>>(
      Xhi, Xlo, 32, W(6), L(6), 32, anb[0], nullptr, H1h, H1l, HP, nullptr, HD, 1);
  gemm_mfma<true,  false, true ><<<dim3(GR, 5), gblk, 0, stream>>>(
      H1h, H1l, HP, W(7), L(7), HP, anb[1], nullptr, H2h, H2l, HP, nullptr, HD, 10);
  gemm_mfma<true,  false, true ><<<dim3(GR, 5), gblk, 0, stream>>>(
      H2h, H2l, HP, W(8), L(8), HP, anb[2], nullptr, H1h, H1l, HP, nullptr, HD, 10);
  gemm_mfma<true,  false, true ><<<dim3(GR, 5), gblk, 0, stream>>>(
      H1h, H1l, HP, W(9), L(9), HP, anb[3], nullptr, H2h, H2l, HP, nullptr, HD, 10);
  gemm_mfma<true,  false, true ><<<dim3(GR, 5), gblk, 0, stream>>>(
      H2h, H2l, HP, W(10), L(10), HP, anb[4], nullptr, H1h, H1l, HP, nullptr, HD, 10);
  gemm_mfma<false, true,  false><<<dim3(GR, 1), gblk, 0, stream>>>(
      H1h, H1l, HP, W(11), L(11), HP, anb[5], Xf, nullptr, nullptr, 0, g_all, GD, 10);

  norms_k<<<NROW / 4, blk, 0, stream>>>(f_all, g_all, fn, gn);
  dist1_k<<<dim3(NXP / 64, NV / 64), blk, 0, stream>>>(
      f_all, g_all, fn, gn, p_eps, p_sig, p_sig0, p_cst, fm, colsum, ss_parts);
  mu_k<<<1, blk, 0, stream>>>(colsum, mu, summu2);
  pass2_k<<<NXP / 4, blk, 0, stream>>>(fm, mu, sz_parts);
  final_k<<<1, 64, 0, stream>>>(ss_parts, sz_parts, summu2, (float*)d_out);
}

// Round 3
// 1233.491 us; speedup vs baseline: 1.5749x; 1.1165x over previous
//
#include <hip/hip_runtime.h>
#include <cstdint>

#define NROW 66560   // 2*NX + J rows through both MLPs
#define NXP  32768   // nx
#define NV   1024    // J
#define FD   100     // dn output dim
#define GD   28      // input / an output dim
#define HD   300     // hidden dim
#define HP   320     // padded hidden dim (k-padding for BK=32)

typedef unsigned short u16;
typedef __bf16 bf16x8 __attribute__((ext_vector_type(8)));
typedef float  f32x4  __attribute__((ext_vector_type(4)));

__device__ inline u16 f2bf(float x) {
  unsigned u = __builtin_bit_cast(unsigned, x);
  unsigned r = (u + 0x7FFF + ((u >> 16) & 1)) >> 16;
  return (u16)r;
}
__device__ inline float bf2f(u16 h) {
  unsigned u = ((unsigned)h) << 16;
  return __builtin_bit_cast(float, u);
}

// ---------------------------------------------------------------------------
// Prep: assemble [X;Y;V] rows, emit bf16 hi/lo planes (K padded 28->32) and
// fp32 copy (for the an-MLP residual).
// ---------------------------------------------------------------------------
__global__ __launch_bounds__(256) void prep_x(
    const float* __restrict__ XY, const float* __restrict__ V,
    u16* __restrict__ Xhi, u16* __restrict__ Xlo, float* __restrict__ Xf)
{
  int gid = blockIdx.x * 256 + threadIdx.x;   // NROW*32 total
  int row = gid >> 5, k = gid & 31;
  if (row >= NROW) return;
  float v = 0.f;
  if (k < GD) v = (row < 2 * NXP) ? XY[(size_t)row * GD + k]
                                  : V[(size_t)(row - 2 * NXP) * GD + k];
  u16 hi = f2bf(v);
  u16 lo = f2bf(v - bf2f(hi));
  Xhi[(size_t)row * 32 + k] = hi;
  Xlo[(size_t)row * 32 + k] = lo;
  if (k < GD) Xf[(size_t)row * GD + k] = v;
}

// ---------------------------------------------------------------------------
// Prep: transpose + split + zero-pad all 12 weight matrices. Wt[m][k] layout.
// ---------------------------------------------------------------------------
struct WDesc { const float* W; u16* hi; u16* lo; int K, M, Kpad, Mpad; };
struct WAll  { WDesc d[12]; };

__global__ __launch_bounds__(256) void prep_w(WAll wa)
{
  WDesc d = wa.d[blockIdx.y];
  int gid = blockIdx.x * 256 + threadIdx.x;
  if (gid >= d.Kpad * d.Mpad) return;
  int m = gid / d.Kpad, k = gid - m * d.Kpad;
  float v = (k < d.K && m < d.M) ? d.W[(size_t)k * d.M + m] : 0.f;
  u16 hi = f2bf(v);
  u16 lo = f2bf(v - bf2f(hi));
  d.hi[(size_t)m * d.Kpad + k] = hi;
  d.lo[(size_t)m * d.Kpad + k] = lo;
}

// ---------------------------------------------------------------------------
// WIDE split-bf16 MFMA GEMM for N=320 layers: C = relu(A @ Wt + bias),
// output written as hi/lo bf16 planes (stride HP).
// BM=64, BN=320 (full width -> A read ONCE per layer), BK=32.
// 256 threads = 4 waves; wave w owns cols [80w, 80w+80) = 5 MFMA col-tiles,
// all 64 rows = 4 row-tiles. acc 4x5 f32x4.
// B staged in ONE 320x40 LDS buffer, two passes per chunk:
//   pass1 (Bh): acc += Ah*Bh + Al*Bh ; pass2 (Bl): acc += Ah*Bl.
// LDS = 2*5.1KB (A hi/lo) + 25.6KB (B) = 35.9KB -> 3-4 blocks/CU.
// ---------------------------------------------------------------------------
__global__ __launch_bounds__(256) void gemm_w(
    const u16* __restrict__ Ahi, const u16* __restrict__ Alo, int sA,
    const u16* __restrict__ Bhi, const u16* __restrict__ Blo, int sW,
    const float* __restrict__ bias,
    u16* __restrict__ Chi, u16* __restrict__ Clo, int Kch)
{
  __shared__ u16 AsH[64 * 40], AsL[64 * 40], Bs[320 * 40];
  const int tid  = threadIdx.x;
  const int lane = tid & 63, wave = tid >> 6;
  const int m16  = lane & 15, quad = lane >> 4;
  const int row0 = blockIdx.x * 64;

  f32x4 acc[4][5];
#pragma unroll
  for (int i = 0; i < 4; ++i)
#pragma unroll
    for (int j = 0; j < 5; ++j) acc[i][j] = (f32x4)0.f;

  for (int ch = 0; ch < Kch; ++ch) {
    const int k0 = ch * 32;
    __syncthreads();   // pass-2 readers of previous chunk done
    // stage A (both planes): 64 rows x 32k, 256 uint4 per plane, 1/thread
    {
      int r = tid >> 2, kc = tid & 3;
      uint4 h = *reinterpret_cast<const uint4*>(&Ahi[(size_t)(row0 + r) * sA + k0 + kc * 8]);
      uint4 l = *reinterpret_cast<const uint4*>(&Alo[(size_t)(row0 + r) * sA + k0 + kc * 8]);
      *reinterpret_cast<uint4*>(&AsH[r * 40 + kc * 8]) = h;
      *reinterpret_cast<uint4*>(&AsL[r * 40 + kc * 8]) = l;
    }
    // stage Bh: 320 rows x 32k = 1280 uint4, 5/thread
#pragma unroll
    for (int i = 0; i < 5; ++i) {
      int id = tid + i * 256;
      int r = id >> 2, kc = id & 3;
      uint4 h = *reinterpret_cast<const uint4*>(&Bhi[(size_t)r * sW + k0 + kc * 8]);
      *reinterpret_cast<uint4*>(&Bs[r * 40 + kc * 8]) = h;
    }
    __syncthreads();

    bf16x8 ah[4], al[4];
#pragma unroll
    for (int i = 0; i < 4; ++i) {
      int off = (i * 16 + m16) * 40 + quad * 8;
      ah[i] = *reinterpret_cast<const bf16x8*>(&AsH[off]);
      al[i] = *reinterpret_cast<const bf16x8*>(&AsL[off]);
    }
    // pass 1: Bh terms
#pragma unroll
    for (int j = 0; j < 5; ++j) {
      bf16x8 bh = *reinterpret_cast<const bf16x8*>(&Bs[(wave * 80 + j * 16 + m16) * 40 + quad * 8]);
#pragma unroll
      for (int i = 0; i < 4; ++i) {
        acc[i][j] = __builtin_amdgcn_mfma_f32_16x16x32_bf16(ah[i], bh, acc[i][j], 0, 0, 0);
        acc[i][j] = __builtin_amdgcn_mfma_f32_16x16x32_bf16(al[i], bh, acc[i][j], 0, 0, 0);
      }
    }
    __syncthreads();   // pass-1 reads done before Bs overwrite
    // stage Bl
#pragma unroll
    for (int i = 0; i < 5; ++i) {
      int id = tid + i * 256;
      int r = id >> 2, kc = id & 3;
      uint4 l = *reinterpret_cast<const uint4*>(&Blo[(size_t)r * sW + k0 + kc * 8]);
      *reinterpret_cast<uint4*>(&Bs[r * 40 + kc * 8]) = l;
    }
    __syncthreads();
    // pass 2: Ah*Bl
#pragma unroll
    for (int j = 0; j < 5; ++j) {
      bf16x8 bl = *reinterpret_cast<const bf16x8*>(&Bs[(wave * 80 + j * 16 + m16) * 40 + quad * 8]);
#pragma unroll
      for (int i = 0; i < 4; ++i)
        acc[i][j] = __builtin_amdgcn_mfma_f32_16x16x32_bf16(ah[i], bl, acc[i][j], 0, 0, 0);
    }
  }

  // epilogue: C/D layout col=lane&15, row=quad*4+reg (m89-verified)
#pragma unroll
  for (int j = 0; j < 5; ++j) {
    int col = wave * 80 + j * 16 + m16;
    float bv = (col < HD) ? bias[col] : 0.f;   // padded cols stay exactly 0
#pragma unroll
    for (int i = 0; i < 4; ++i) {
#pragma unroll
      for (int r = 0; r < 4; ++r) {
        int row = row0 + i * 16 + quad * 4 + r;
        float x = fmaxf(acc[i][j][r] + bv, 0.f);
        u16 hi = f2bf(x);
        u16 lo = f2bf(x - bf2f(hi));
        Chi[(size_t)row * HP + col] = hi;
        Clo[(size_t)row * HP + col] = lo;
      }
    }
  }
}

// ---------------------------------------------------------------------------
// Narrow split-bf16 MFMA GEMM (final layers, small N, fp32 out [+resid]).
// BM=128, BN=64, BK=32; 128 threads = 2 waves.
// ---------------------------------------------------------------------------
template<bool RELU, bool RESID, bool SPLIT>
__global__ __launch_bounds__(128) void gemm_mfma(
    const u16* __restrict__ Ahi, const u16* __restrict__ Alo, int sA,
    const u16* __restrict__ Bhi, const u16* __restrict__ Blo, int sB,
    const float* __restrict__ bias, const float* __restrict__ resid,
    u16* __restrict__ Chi, u16* __restrict__ Clo, int sC,
    float* __restrict__ Cf, int Mreal, int Kch)
{
  __shared__ u16 AsH[128 * 40], AsL[128 * 40], BsH[64 * 40], BsL[64 * 40];
  const int tid  = threadIdx.x;
  const int lane = tid & 63, wave = tid >> 6;
  const int m16  = lane & 15, quad = lane >> 4;
  const int row0 = blockIdx.x * 128;
  const int col0 = blockIdx.y * 64;

  f32x4 acc[4][4];
#pragma unroll
  for (int i = 0; i < 4; ++i)
#pragma unroll
    for (int j = 0; j < 4; ++j) acc[i][j] = (f32x4)0.f;

  for (int ch = 0; ch < Kch; ++ch) {
    const int k0 = ch * 32;
    __syncthreads();
#pragma unroll
    for (int i = 0; i < 4; ++i) {
      int id = tid + i * 128;
      int r = id >> 2, kc = id & 3;
      uint4 h = *reinterpret_cast<const uint4*>(&Ahi[(size_t)(row0 + r) * sA + k0 + kc * 8]);
      uint4 l = *reinterpret_cast<const uint4*>(&Alo[(size_t)(row0 + r) * sA + k0 + kc * 8]);
      *reinterpret_cast<uint4*>(&AsH[r * 40 + kc * 8]) = h;
      *reinterpret_cast<uint4*>(&AsL[r * 40 + kc * 8]) = l;
    }
#pragma unroll
    for (int i = 0; i < 2; ++i) {
      int id = tid + i * 128;
      int r = id >> 2, kc = id & 3;
      uint4 h = *reinterpret_cast<const uint4*>(&Bhi[(size_t)(col0 + r) * sB + k0 + kc * 8]);
      uint4 l = *reinterpret_cast<const uint4*>(&Blo[(size_t)(col0 + r) * sB + k0 + kc * 8]);
      *reinterpret_cast<uint4*>(&BsH[r * 40 + kc * 8]) = h;
      *reinterpret_cast<uint4*>(&BsL[r * 40 + kc * 8]) = l;
    }
    __syncthreads();

    bf16x8 ah[4], al[4], bh[4], bl[4];
#pragma unroll
    for (int i = 0; i < 4; ++i) {
      int off = (wave * 64 + i * 16 + m16) * 40 + quad * 8;
      ah[i] = *reinterpret_cast<const bf16x8*>(&AsH[off]);
      al[i] = *reinterpret_cast<const bf16x8*>(&AsL[off]);
    }
#pragma unroll
    for (int j = 0; j < 4; ++j) {
      int off = (j * 16 + m16) * 40 + quad * 8;
      bh[j] = *reinterpret_cast<const bf16x8*>(&BsH[off]);
      bl[j] = *reinterpret_cast<const bf16x8*>(&BsL[off]);
    }
#pragma unroll
    for (int i = 0; i < 4; ++i)
#pragma unroll
      for (int j = 0; j < 4; ++j) {
        acc[i][j] = __builtin_amdgcn_mfma_f32_16x16x32_bf16(ah[i], bh[j], acc[i][j], 0, 0, 0);
        acc[i][j] = __builtin_amdgcn_mfma_f32_16x16x32_bf16(ah[i], bl[j], acc[i][j], 0, 0, 0);
        acc[i][j] = __builtin_amdgcn_mfma_f32_16x16x32_bf16(al[i], bh[j], acc[i][j], 0, 0, 0);
      }
  }

#pragma unroll
  for (int j = 0; j < 4; ++j) {
    int col = col0 + j * 16 + m16;
    float bv = (col < Mreal) ? bias[col] : 0.f;
#pragma unroll
    for (int i = 0; i < 4; ++i) {
#pragma unroll
      for (int r = 0; r < 4; ++r) {
        int row = row0 + wave * 64 + i * 16 + quad * 4 + r;
        float x = acc[i][j][r] + bv;
        if (RELU) x = fmaxf(x, 0.f);
        if (SPLIT) {
          u16 hi = f2bf(x);
          u16 lo = f2bf(x - bf2f(hi));
          Chi[(size_t)row * sC + col] = hi;
          Clo[(size_t)row * sC + col] = lo;
        } else if (col < Mreal) {
          if (RESID) x += resid[(size_t)row * Mreal + col];
          Cf[(size_t)row * Mreal + col] = x;
        }
      }
    }
  }
}

// ---------------------------------------------------------------------------
// Row squared-norms of f_all (100 dims) and g_all (28 dims). One wave per row.
// ---------------------------------------------------------------------------
__global__ __launch_bounds__(256) void norms_k(
    const float* __restrict__ f_all, const float* __restrict__ g_all,
    float* __restrict__ fn, float* __restrict__ gn)
{
  int wave = threadIdx.x >> 6, lane = threadIdx.x & 63;
  int row = blockIdx.x * 4 + wave;
  const float* f = f_all + (size_t)row * FD;
  const float* g = g_all + (size_t)row * GD;
  float s = f[lane] * f[lane];
  if (lane < FD - 64) { float t = f[lane + 64]; s += t * t; }
  float sg = 0.f;
  if (lane < GD) { float t = g[lane]; sg = t * t; }
#pragma unroll
  for (int m = 32; m >= 1; m >>= 1) { s += __shfl_xor(s, m); sg += __shfl_xor(sg, m); }
  if (lane == 0) { fn[row] = s; gn[row] = sg; }
}

// ---------------------------------------------------------------------------
// Pass 1: fused pdist2 + kernel + fm write + colsum/ss partial reductions.
// ---------------------------------------------------------------------------
__global__ __launch_bounds__(256) void dist1_k(
    const float* __restrict__ f_all, const float* __restrict__ g_all,
    const float* __restrict__ fn, const float* __restrict__ gn,
    const float* __restrict__ p_eps, const float* __restrict__ p_sig,
    const float* __restrict__ p_sig0, const float* __restrict__ p_cst,
    float* __restrict__ fm, double* __restrict__ colsum,
    double* __restrict__ ss_parts)
{
  __shared__ float Xs[GD][68], Ys[GD][68], Vs[GD][68];
  __shared__ float fnX[64], fnY[64], fnV[64], gnX[64], gnY[64], gnV[64];
  __shared__ float red[16][68];
  __shared__ float ssred[4];
  const int tid = threadIdx.x;
  const int tx = tid & 15, ty = tid >> 4;
  const int i0 = blockIdx.x * 64, j0 = blockIdx.y * 64;

  if (tid < 64) {
    fnX[tid] = fn[i0 + tid]; fnY[tid] = fn[NXP + i0 + tid]; fnV[tid] = fn[2 * NXP + j0 + tid];
    gnX[tid] = gn[i0 + tid]; gnY[tid] = gn[NXP + i0 + tid]; gnV[tid] = gn[2 * NXP + j0 + tid];
  }

  float Sxf[4][4] = {}, Syf[4][4] = {}, Sxg[4][4] = {}, Syg[4][4] = {};
  const float* fX = f_all;
  const float* fY = f_all + (size_t)NXP * FD;
  const float* fV = f_all + (size_t)2 * NXP * FD;
  const float* gX = g_all;
  const float* gY = g_all + (size_t)NXP * GD;
  const float* gV = g_all + (size_t)2 * NXP * GD;

  for (int k0 = 0; k0 < FD; k0 += 20) {
    __syncthreads();
    for (int l = tid; l < 320; l += 256) {
      int r = l / 5, kc = l % 5;
      float4 a = *reinterpret_cast<const float4*>(&fX[(size_t)(i0 + r) * FD + k0 + kc * 4]);
      float4 b = *reinterpret_cast<const float4*>(&fY[(size_t)(i0 + r) * FD + k0 + kc * 4]);
      float4 c = *reinterpret_cast<const float4*>(&fV[(size_t)(j0 + r) * FD + k0 + kc * 4]);
      Xs[kc*4+0][r]=a.x; Xs[kc*4+1][r]=a.y; Xs[kc*4+2][r]=a.z; Xs[kc*4+3][r]=a.w;
      Ys[kc*4+0][r]=b.x; Ys[kc*4+1][r]=b.y; Ys[kc*4+2][r]=b.z; Ys[kc*4+3][r]=b.w;
      Vs[kc*4+0][r]=c.x; Vs[kc*4+1][r]=c.y; Vs[kc*4+2][r]=c.z; Vs[kc*4+3][r]=c.w;
    }
    __syncthreads();
#pragma unroll
    for (int kk = 0; kk < 20; ++kk) {
      float4 ax = *reinterpret_cast<const float4*>(&Xs[kk][ty * 4]);
      float4 ay = *reinterpret_cast<const float4*>(&Ys[kk][ty * 4]);
      float4 bv = *reinterpret_cast<const float4*>(&Vs[kk][tx * 4]);
      float axv[4] = {ax.x, ax.y, ax.z, ax.w};
      float ayv[4] = {ay.x, ay.y, ay.z, ay.w};
      float bvv[4] = {bv.x, bv.y, bv.z, bv.w};
#pragma unroll
      for (int i = 0; i < 4; ++i)
#pragma unroll
        for (int j = 0; j < 4; ++j) {
          Sxf[i][j] = fmaf(axv[i], bvv[j], Sxf[i][j]);
          Syf[i][j] = fmaf(ayv[i], bvv[j], Syf[i][j]);
        }
    }
  }

  __syncthreads();
  for (int l = tid; l < 448; l += 256) {
    int r = l / 7, kc = l % 7;
    float4 a = *reinterpret_cast<const float4*>(&gX[(size_t)(i0 + r) * GD + kc * 4]);
    float4 b = *reinterpret_cast<const float4*>(&gY[(size_t)(i0 + r) * GD + kc * 4]);
    float4 c = *reinterpret_cast<const float4*>(&gV[(size_t)(j0 + r) * GD + kc * 4]);
    Xs[kc*4+0][r]=a.x; Xs[kc*4+1][r]=a.y; Xs[kc*4+2][r]=a.z; Xs[kc*4+3][r]=a.w;
    Ys[kc*4+0][r]=b.x; Ys[kc*4+1][r]=b.y; Ys[kc*4+2][r]=b.z; Ys[kc*4+3][r]=b.w;
    Vs[kc*4+0][r]=c.x; Vs[kc*4+1][r]=c.y; Vs[kc*4+2][r]=c.z; Vs[kc*4+3][r]=c.w;
  }
  __syncthreads();
#pragma unroll
  for (int kk = 0; kk < GD; ++kk) {
    float4 ax = *reinterpret_cast<const float4*>(&Xs[kk][ty * 4]);
    float4 ay = *reinterpret_cast<const float4*>(&Ys[kk][ty * 4]);
    float4 bv = *reinterpret_cast<const float4*>(&Vs[kk][tx * 4]);
    float axv[4] = {ax.x, ax.y, ax.z, ax.w};
    float ayv[4] = {ay.x, ay.y, ay.z, ay.w};
    float bvv[4] = {bv.x, bv.y, bv.z, bv.w};
#pragma unroll
    for (int i = 0; i < 4; ++i)
#pragma unroll
      for (int j = 0; j < 4; ++j) {
        Sxg[i][j] = fmaf(axv[i], bvv[j], Sxg[i][j]);
        Syg[i][j] = fmaf(ayv[i], bvv[j], Syg[i][j]);
      }
  }

  float ep  = 1.f / (1.f + __expf(-p_eps[0]));
  float sg  = p_sig[0] * p_sig[0];
  float sg0 = p_sig0[0] * p_sig0[0];
  float cst = p_cst[0];
  float nis = -1.f / sg, nis0 = -1.f / sg0;
  float omep = 1.f - ep;
  float ss = 0.f;
  float colp[4] = {0.f, 0.f, 0.f, 0.f};
#pragma unroll
  for (int i = 0; i < 4; ++i) {
    float vout[4];
    float fx = fnX[ty*4+i], fy = fnY[ty*4+i];
    float gx = gnX[ty*4+i], gy = gnY[ty*4+i];
#pragma unroll
    for (int j = 0; j < 4; ++j) {
      float fv = fnV[tx*4+j], gv = gnV[tx*4+j];
      float dxf = fmaxf(fx + fv - 2.f * Sxf[i][j], 0.f);
      float dxg = fmaxf(gx + gv - 2.f * Sxg[i][j], 0.f);
      float dyf = fmaxf(fy + fv - 2.f * Syf[i][j], 0.f);
      float dyg = fmaxf(gy + gv - 2.f * Syg[i][j], 0.f);
      float kx = cst * (omep * __expf(dxf * nis0) + ep) * __expf(dxg * nis);
      float ky = cst * (omep * __expf(dyf * nis0) + ep) * __expf(dyg * nis);
      float fmv = (kx - ky) * 0.03125f;
      vout[j] = fmv;
      ss = fmaf(fmv, fmv, ss);
      colp[j] += fmv;
    }
    *reinterpret_cast<float4*>(&fm[(size_t)(i0 + ty * 4 + i) * NV + j0 + tx * 4]) =
        make_float4(vout[0], vout[1], vout[2], vout[3]);
  }
#pragma unroll
  for (int m = 32; m >= 1; m >>= 1) ss += __shfl_xor(ss, m);
  if ((tid & 63) == 0) ssred[tid >> 6] = ss;
#pragma unroll
  for (int j = 0; j < 4; ++j) red[ty][tx * 4 + j] = colp[j];
  __syncthreads();
  if (tid < 64) {
    float s = 0.f;
#pragma unroll
    for (int t = 0; t < 16; ++t) s += red[t][tid];
    atomicAdd(&colsum[j0 + tid], (double)s);
  }
  if (tid == 0) {
    double v = (double)ssred[0] + ssred[1] + ssred[2] + ssred[3];
    atomicAdd(&ss_parts[blockIdx.x & 63], v);
  }
}

__global__ __launch_bounds__(256) void mu_k(
    const double* __restrict__ colsum, float* __restrict__ mu,
    double* __restrict__ summu2)
{
  __shared__ double wred[4];
  double local = 0.0;
  for (int j = threadIdx.x; j < NV; j += 256) {
    double m = colsum[j] * (1.0 / (double)NXP);
    mu[j] = (float)m;
    local += m * m;
  }
  int lane = threadIdx.x & 63, wave = threadIdx.x >> 6;
#pragma unroll
  for (int m = 32; m >= 1; m >>= 1) local += __shfl_xor(local, m);
  if (lane == 0) wred[wave] = local;
  __syncthreads();
  if (threadIdx.x == 0) *summu2 = wred[0] + wred[1] + wred[2] + wred[3];
}

__global__ __launch_bounds__(256) void pass2_k(
    const float* __restrict__ fm, const float* __restrict__ mu,
    double* __restrict__ sz_parts)
{
  __shared__ float4 mus[NV / 4];
  for (int l = threadIdx.x; l < NV / 4; l += 256)
    mus[l] = reinterpret_cast<const float4*>(mu)[l];
  __syncthreads();
  __shared__ double zb[4];
  int wave = threadIdx.x >> 6, lane = threadIdx.x & 63;
  int row = blockIdx.x * 4 + wave;
  const float4* frow = reinterpret_cast<const float4*>(fm + (size_t)row * NV);
  float z = 0.f;
#pragma unroll
  for (int it = 0; it < 4; ++it) {
    float4 f = frow[lane + 64 * it];
    float4 m = mus[lane + 64 * it];
    z = fmaf(f.x, m.x, z); z = fmaf(f.y, m.y, z);
    z = fmaf(f.z, m.z, z); z = fmaf(f.w, m.w, z);
  }
#pragma unroll
  for (int m = 32; m >= 1; m >>= 1) z += __shfl_xor(z, m);
  if (lane == 0) zb[wave] = (double)z * (double)z;
  __syncthreads();
  if (threadIdx.x == 0)
    atomicAdd(&sz_parts[blockIdx.x & 63], zb[0] + zb[1] + zb[2] + zb[3]);
}

__global__ __launch_bounds__(64) void final_k(
    const double* __restrict__ ss_parts, const double* __restrict__ sz_parts,
    const double* __restrict__ summu2, float* __restrict__ out)
{
  int lane = threadIdx.x;
  double ss = ss_parts[lane], sz = sz_parts[lane];
#pragma unroll
  for (int m = 32; m >= 1; m >>= 1) { ss += __shfl_xor(ss, m); sz += __shfl_xor(sz, m); }
  if (lane == 0) {
    double smu2 = *summu2;
    const double nx = (double)NXP;
    double t1 = smu2 * nx / (nx - 1.0);
    double t2 = ss / (nx * (nx - 1.0));
    double um = t1 - t2;
    double uv = 4.0 * (sz / nx) - 4.0 * smu2 * smu2;
    out[0] = (float)(-(um / sqrt(uv + 1e-6)));
  }
}

// ---------------------------------------------------------------------------
extern "C" void kernel_launch(void* const* d_in, const int* in_sizes, int n_in,
                              void* d_out, int out_size, void* d_ws, size_t ws_size,
                              hipStream_t stream)
{
  (void)in_sizes; (void)n_in; (void)out_size; (void)ws_size;
  const float* XY = (const float*)d_in[0];
  const float* V  = (const float*)d_in[1];
  const float* dnW[6]; const float* dnb[6]; const float* anW[6]; const float* anb[6];
  for (int i = 0; i < 6; ++i) {
    dnW[i] = (const float*)d_in[2 + 2 * i];  dnb[i] = (const float*)d_in[3 + 2 * i];
    anW[i] = (const float*)d_in[14 + 2 * i]; anb[i] = (const float*)d_in[15 + 2 * i];
  }
  const float* p_eps  = (const float*)d_in[26];
  const float* p_sig  = (const float*)d_in[27];
  const float* p_sig0 = (const float*)d_in[28];
  const float* p_cst  = (const float*)d_in[29];

  char* base = (char*)d_ws;
  size_t off = 0;
  auto alloc = [&](size_t b) { size_t o = off; off += (b + 255) & ~(size_t)255; return o; };
  float* Xf    = (float*)(base + alloc((size_t)NROW * GD * 4));
  u16*   Xhi   = (u16*)  (base + alloc((size_t)NROW * 32 * 2));
  u16*   Xlo   = (u16*)  (base + alloc((size_t)NROW * 32 * 2));
  float* f_all = (float*)(base + alloc((size_t)NROW * FD * 4));
  float* g_all = (float*)(base + alloc((size_t)NROW * GD * 4));
  float* fn    = (float*)(base + alloc((size_t)NROW * 4));
  float* gn    = (float*)(base + alloc((size_t)NROW * 4));
  float* mu    = (float*)(base + alloc((size_t)NV * 4));
  size_t zoff = off;
  double* colsum   = (double*)(base + alloc(NV * 8));
  double* ss_parts = (double*)(base + alloc(64 * 8));
  double* sz_parts = (double*)(base + alloc(64 * 8));
  double* summu2   = (double*)(base + alloc(8));
  size_t zbytes = off - zoff;
  u16* Whi = (u16*)(base + alloc((size_t)12 * HP * HP * 2));
  u16* Wlo = (u16*)(base + alloc((size_t)12 * HP * HP * 2));
  u16* H1h = (u16*)(base + alloc((size_t)NROW * HP * 2));
  u16* H1l = (u16*)(base + alloc((size_t)NROW * HP * 2));
  u16* H2h = (u16*)(base + alloc((size_t)NROW * HP * 2));
  u16* H2l = (u16*)(base + alloc((size_t)NROW * HP * 2));
  float* fm = (float*)H1h;  // overlay: 134.2 MB <= 4 x 42.6 MB contiguous

  hipMemsetAsync(base + zoff, 0, zbytes, stream);

  dim3 blk(256);
  prep_x<<<NROW * 32 / 256, blk, 0, stream>>>(XY, V, Xhi, Xlo, Xf);

  WAll wa;
  auto wslot = [&](int s, u16** hi, u16** lo) {
    *hi = Whi + (size_t)s * HP * HP; *lo = Wlo + (size_t)s * HP * HP;
  };
  for (int i = 0; i < 6; ++i) {
    u16 *hi, *lo; wslot(i, &hi, &lo);
    int K = (i == 0) ? GD : HD, M = (i == 5) ? FD : HD;
    int Kp = (i == 0) ? 32 : HP, Mp = (i == 5) ? 128 : HP;
    wa.d[i] = {dnW[i], hi, lo, K, M, Kp, Mp};
  }
  for (int i = 0; i < 6; ++i) {
    u16 *hi, *lo; wslot(6 + i, &hi, &lo);
    int K = (i == 0) ? GD : HD, M = (i == 5) ? GD : HD;
    int Kp = (i == 0) ? 32 : HP, Mp = (i == 5) ? 64 : HP;
    wa.d[6 + i] = {anW[i], hi, lo, K, M, Kp, Mp};
  }
  prep_w<<<dim3((HP * HP + 255) / 256, 12), blk, 0, stream>>>(wa);

  auto W = [&](int s) { return Whi + (size_t)s * HP * HP; };
  auto L = [&](int s) { return Wlo + (size_t)s * HP * HP; };
  const int GW = NROW / 64;   // 1040 row blocks for wide kernel
  const int GR = NROW / 128;  // 520 for narrow kernel

  // dn MLP -> f_all
  gemm_w<<<GW, blk, 0, stream>>>(Xhi, Xlo, 32, W(0), L(0), 32, dnb[0], H1h, H1l, 1);
  gemm_w<<<GW, blk, 0, stream>>>(H1h, H1l, HP, W(1), L(1), HP, dnb[1], H2h, H2l, 10);
  gemm_w<<<GW, blk, 0, stream>>>(H2h, H2l, HP, W(2), L(2), HP, dnb[2], H1h, H1l, 10);
  gemm_w<<<GW, blk, 0, stream>>>(H1h, H1l, HP, W(3), L(3), HP, dnb[3], H2h, H2l, 10);
  gemm_w<<<GW, blk, 0, stream>>>(H2h, H2l, HP, W(4), L(4), HP, dnb[4], H1h, H1l, 10);
  gemm_mfma<false, false, false><<<dim3(GR, 2), dim3(128), 0, stream>>>(
      H1h, H1l, HP, W(5), L(5), HP, dnb[5], nullptr, nullptr, nullptr, 0, f_all, FD, 10);
  // an MLP (+x residual) -> g_all
  gemm_w<<<GW, blk, 0, stream>>>(Xhi, Xlo, 32, W(6), L(6), 32, anb[0], H1h, H1l, 1);
  gemm_w<<<GW, blk, 0, stream>>>(H1h, H1l, HP, W(7), L(7), HP, anb[1], H2h, H2l, 10);
  gemm_w<<<GW, blk, 0, stream>>>(H2h, H2l, HP, W(8), L(8), HP, anb[2], H1h, H1l, 10);
  gemm_w<<<GW, blk, 0, stream>>>(H1h, H1l, HP, W(9), L(9), HP, anb[3], H2h, H2l, 10);
  gemm_w<<<GW, blk, 0, stream>>>(H2h, H2l, HP, W(10), L(10), HP, anb[4], H1h, H1l, 10);
  gemm_mfma<false, true, false><<<dim3(GR, 1), dim3(128), 0, stream>>>(
      H1h, H1l, HP, W(11), L(11), HP, anb[5], Xf, nullptr, nullptr, 0, g_all, GD, 10);

  norms_k<<<NROW / 4, blk, 0, stream>>>(f_all, g_all, fn, gn);
  dist1_k<<<dim3(NXP / 64, NV / 64), blk, 0, stream>>>(
      f_all, g_all, fn, gn, p_eps, p_sig, p_sig0, p_cst, fm, colsum, ss_parts);
  mu_k<<<1, blk, 0, stream>>>(colsum, mu, summu2);
  pass2_k<<<NXP / 4, blk, 0, stream>>>(fm, mu, sz_parts);
  final_k<<<1, 64, 0, stream>>>(ss_parts, sz_parts, summu2, (float*)d_out);
}